// Round 1
// 542.260 us; speedup vs baseline: 1.0728x; 1.0728x over previous
//
#include <hip/hip_runtime.h>
#include <hip/hip_bf16.h>

// AttentionLayer: T=128, N=2048, D=256, w=3
// out[i] = x[i]                                  for i < 3
// out[i,n,:] = sum_j p[i-3+j,n] * x[i-3+j,n,:]   for i >= 3
// p[t,:] = softmax_n( sum_e proj[e]*tanh( (x[t] @ W)[n,e] ) )
//
// R1 redesign of gemm_s_kernel:
//  - one block covers ALL 256 e-columns (BM=256, 512 thr, 8 waves x 32 rows)
//  - W LDS-resident in two 64KB K-halves (static LDS), XOR-swizzled
//    (byte ^= (e&7)<<4) so ds_read_b128 B-frags are conflict-free
//  - A fragments loaded DIRECTLY from global in MFMA layout, converted
//    fp32->bf16 in registers, 2-deep prefetch -> zero barriers in K-loop
//  - x read exactly once; no atomics, no memset; direct s store
//  - cheap exp-based tanh in epilogue
// R1 out_kernel: t tiled by 32 (grid.y=4 -> 2048 blocks, 32 waves/CU)

#define T_DIM 128
#define N_DIM 2048
#define D_DIM 256
#define TS 127              // number of s/p slices (t = 0..126)
#define M_TOT (TS * N_DIM)  // 260096 rows in the fused GEMM
#define BM 256
#define TB 32

typedef __attribute__((ext_vector_type(8))) short bf16x8;
typedef __attribute__((ext_vector_type(4))) float f32x4;

__device__ inline short f2bf(float f) {
  union { float f; unsigned u; } v; v.f = f;
  unsigned r = v.u + 0x7FFFu + ((v.u >> 16) & 1u);  // round-nearest-even
  return (short)(r >> 16);
}

__device__ inline bf16x8 cvt8(const float4 a, const float4 b) {
  bf16x8 r;
  r[0] = f2bf(a.x); r[1] = f2bf(a.y); r[2] = f2bf(a.z); r[3] = f2bf(a.w);
  r[4] = f2bf(b.x); r[5] = f2bf(b.y); r[6] = f2bf(b.z); r[7] = f2bf(b.w);
  return r;
}

// tanh(x) = (e^{2x}-1)/(e^{2x}+1); clamp avoids inf/inf. |err| ~1e-7.
__device__ inline float fast_tanh(float x) {
  float e = __expf(fminf(2.0f * x, 30.0f));
  return __fdividef(e - 1.0f, e + 1.0f);
}

// ---------------- k0: W (fp32, d x e) -> Wt (bf16, e x d) ----------------
__global__ __launch_bounds__(256) void prep_kernel(const float* __restrict__ W,
                                                   short* __restrict__ Wt) {
  int id = blockIdx.x * 256 + threadIdx.x;   // 65536 total
  int d = id >> 8;
  int e = id & 255;
  Wt[e * 256 + d] = f2bf(W[d * 256 + e]);
}

// ---------------- k1: fused GEMM + tanh + proj-reduce -> s[m] ------------
// 512 threads = 8 waves, each wave owns 32 m-rows x all 256 e-cols.
// acc: 2 row-frags x 16 e-frags of 16x16x32 MFMA = 128 VGPR f32.
__global__ __launch_bounds__(512) void gemm_s_kernel(const float* __restrict__ x,
                                                     const short* __restrict__ Wt,
                                                     const float* __restrict__ proj,
                                                     float* __restrict__ s) {
  __shared__ short Ws[256 * 128];  // 64KB: one K-half of W, e-major, swizzled

  const int tid = threadIdx.x;
  const int lane = tid & 63;
  const int w = tid >> 6;          // wave 0..7
  const int quad = lane >> 4;      // k-group within frag
  const int l15 = lane & 15;       // row (A) / e-col (B) within frag
  const int m0 = blockIdx.x * BM;
  const size_t row0 = (size_t)(m0 + w * 32 + l15);
  const float* xp = x + row0 * D_DIM + quad * 8;
  const int swzc = (l15 & 7) << 4;

  // 2-deep A prefetch: A0 holds k-tile kg (even), A1 holds kg (odd)
  float4 A0[2][2], A1[2][2];
  A0[0][0] = *(const float4*)(xp);
  A0[0][1] = *(const float4*)(xp + 4);
  A0[1][0] = *(const float4*)(xp + 16 * D_DIM);
  A0[1][1] = *(const float4*)(xp + 16 * D_DIM + 4);
  A1[0][0] = *(const float4*)(xp + 32);
  A1[0][1] = *(const float4*)(xp + 36);
  A1[1][0] = *(const float4*)(xp + 32 + 16 * D_DIM);
  A1[1][1] = *(const float4*)(xp + 36 + 16 * D_DIM);

  f32x4 acc[2][16] = {};

#pragma unroll
  for (int half = 0; half < 2; ++half) {
    if (half) __syncthreads();  // all waves done reading previous half
    // stage 64KB of Wt: 4096 x 16B slots over 512 threads.
    // dst byte = (e*256 + ks*16) ^ ((e&7)<<4)  (XOR bank-swizzle)
#pragma unroll
    for (int it = 0; it < 8; ++it) {
      int slot = tid + it * 512;
      int e = slot >> 4;
      int ks = slot & 15;
      uint4 v = *(const uint4*)(Wt + e * D_DIM + half * 128 + ks * 8);
      int dst = (e * 256 + ks * 16) ^ ((e & 7) << 4);
      *(uint4*)((char*)Ws + dst) = v;
    }
    __syncthreads();

#pragma unroll
    for (int kt = 0; kt < 4; ++kt) {
      const int kg = half * 4 + kt;  // global k-tile 0..7 (32 k each)
      bf16x8 a0, a1;
      if ((kg & 1) == 0) {
        a0 = cvt8(A0[0][0], A0[0][1]);
        a1 = cvt8(A0[1][0], A0[1][1]);
        if (kg < 6) {
          const float* q = xp + (kg + 2) * 32;
          A0[0][0] = *(const float4*)(q);
          A0[0][1] = *(const float4*)(q + 4);
          A0[1][0] = *(const float4*)(q + 16 * D_DIM);
          A0[1][1] = *(const float4*)(q + 16 * D_DIM + 4);
        }
      } else {
        a0 = cvt8(A1[0][0], A1[0][1]);
        a1 = cvt8(A1[1][0], A1[1][1]);
        if (kg < 6) {
          const float* q = xp + (kg + 2) * 32;
          A1[0][0] = *(const float4*)(q);
          A1[0][1] = *(const float4*)(q + 4);
          A1[1][0] = *(const float4*)(q + 16 * D_DIM);
          A1[1][1] = *(const float4*)(q + 16 * D_DIM + 4);
        }
      }
      // B read: byte = e_row*256 + ((kloc*2 + quad*16) ^ swzc), kloc = kt*32
      const int kb = (kt * 64 + quad * 16) ^ swzc;
#pragma unroll
      for (int ef = 0; ef < 16; ++ef) {
        const bf16x8 b =
            *(const bf16x8*)((const char*)Ws + (ef * 16 + l15) * 256 + kb);
        acc[0][ef] = __builtin_amdgcn_mfma_f32_16x16x32_bf16(a0, b, acc[0][ef], 0, 0, 0);
        acc[1][ef] = __builtin_amdgcn_mfma_f32_16x16x32_bf16(a1, b, acc[1][ef], 0, 0, 0);
      }
    }
  }

  // epilogue: s[m] = sum_e tanh(C[m][e]) * proj[e]
  // C/D frag: e-col = ef*16 + l15, m-row = mf*16 + quad*4 + r
  float pj[16];
#pragma unroll
  for (int ef = 0; ef < 16; ++ef) pj[ef] = proj[ef * 16 + l15];

#pragma unroll
  for (int mf = 0; mf < 2; ++mf) {
#pragma unroll
    for (int r = 0; r < 4; ++r) {
      float val = 0.f;
#pragma unroll
      for (int ef = 0; ef < 16; ++ef)
        val = __builtin_fmaf(fast_tanh(acc[mf][ef][r]), pj[ef], val);
#pragma unroll
      for (int off = 1; off < 16; off <<= 1) val += __shfl_xor(val, off);
      if (l15 == 0) s[m0 + w * 32 + mf * 16 + quad * 4 + r] = val;
    }
  }
}

// ---------------- k2: softmax over n (2048) per t ------------------------
__global__ __launch_bounds__(256) void softmax_kernel(const float* __restrict__ s,
                                                      float* __restrict__ p) {
  const int t = blockIdx.x;
  const int tid = threadIdx.x;
  const float* row = s + (size_t)t * N_DIM;
  float v[8];
  float mx = -1e30f;
#pragma unroll
  for (int k = 0; k < 8; ++k) {
    v[k] = row[tid + k * 256];
    mx = fmaxf(mx, v[k]);
  }
#pragma unroll
  for (int off = 1; off < 64; off <<= 1) mx = fmaxf(mx, __shfl_xor(mx, off));
  __shared__ float redm[4];
  if ((tid & 63) == 0) redm[tid >> 6] = mx;
  __syncthreads();
  mx = fmaxf(fmaxf(redm[0], redm[1]), fmaxf(redm[2], redm[3]));

  float sum = 0.f;
#pragma unroll
  for (int k = 0; k < 8; ++k) {
    v[k] = __expf(v[k] - mx);
    sum += v[k];
  }
#pragma unroll
  for (int off = 1; off < 64; off <<= 1) sum += __shfl_xor(sum, off);
  __shared__ float reds[4];
  if ((tid & 63) == 0) reds[tid >> 6] = sum;
  __syncthreads();
  sum = reds[0] + reds[1] + reds[2] + reds[3];
  float inv = 1.0f / sum;
#pragma unroll
  for (int k = 0; k < 8; ++k) p[(size_t)t * N_DIM + tid + k * 256] = v[k] * inv;
}

// ---------------- k3: streaming output, t tiled by TB --------------------
__global__ __launch_bounds__(256) void out_kernel(const float* __restrict__ x,
                                                  const float* __restrict__ p,
                                                  float* __restrict__ out) {
  const int gid = blockIdx.x * 256 + threadIdx.x;  // 131072 = 2048 * 64
  const int n = gid >> 6;
  const int d4 = gid & 63;
  const int t0 = blockIdx.y * TB;
  const size_t base = (size_t)n * D_DIM + d4 * 4;
  const size_t tstride = (size_t)N_DIM * D_DIM;

  float4 x0 = {}, x1 = {}, x2 = {};
  float p0 = 0.f, p1 = 0.f, p2 = 0.f;
  if (t0 >= 3) {  // warm-up: window for the first output of this chunk
    x0 = *(const float4*)(x + (t0 - 3) * tstride + base);
    x1 = *(const float4*)(x + (t0 - 2) * tstride + base);
    x2 = *(const float4*)(x + (t0 - 1) * tstride + base);
    p0 = p[(size_t)(t0 - 3) * N_DIM + n];
    p1 = p[(size_t)(t0 - 2) * N_DIM + n];
    p2 = p[(size_t)(t0 - 1) * N_DIM + n];
  }
  for (int t = t0; t < t0 + TB; ++t) {
    const float4 xc = *(const float4*)(x + t * tstride + base);
    const float pc = (t < TS) ? p[(size_t)t * N_DIM + n] : 0.f;
    float4 o;
    if (t >= 3) {
      o.x = p0 * x0.x + p1 * x1.x + p2 * x2.x;
      o.y = p0 * x0.y + p1 * x1.y + p2 * x2.y;
      o.z = p0 * x0.z + p1 * x1.z + p2 * x2.z;
      o.w = p0 * x0.w + p1 * x1.w + p2 * x2.w;
    } else {
      o = xc;
    }
    *(float4*)(out + t * tstride + base) = o;
    x0 = x1; x1 = x2; x2 = xc;
    p0 = p1; p1 = p2; p2 = pc;
  }
}

extern "C" void kernel_launch(void* const* d_in, const int* in_sizes, int n_in,
                              void* d_out, int out_size, void* d_ws, size_t ws_size,
                              hipStream_t stream) {
  const float* x = (const float*)d_in[0];     // (128, 2048, 256) fp32
  const float* W = (const float*)d_in[1];     // (256, 256) fp32
  const float* proj = (const float*)d_in[2];  // (256, 1) fp32
  // d_in[3] = attention_width = 3 (hardcoded)
  float* out = (float*)d_out;

  // workspace layout
  char* ws = (char*)d_ws;
  short* Wt = (short*)ws;                               // 65536 bf16 = 128 KB
  float* s = (float*)(ws + 131072);                     // 260096 f32 ~ 1 MB
  float* p = (float*)(ws + 131072 + 1040384);           // 260096 f32 ~ 1 MB

  // k0: transpose+convert W (s is fully overwritten by k1 -> no memset)
  hipLaunchKernelGGL(prep_kernel, dim3(256), dim3(256), 0, stream, W, Wt);

  // k1: s[t,n] = sum_e proj[e]*tanh((x[t] @ W)[n,e])
  hipLaunchKernelGGL(gemm_s_kernel, dim3(M_TOT / BM), dim3(512), 0, stream,
                     x, Wt, proj, s);

  // k2: p[t,:] = softmax_n(s[t,:])
  hipLaunchKernelGGL(softmax_kernel, dim3(TS), dim3(256), 0, stream, s, p);

  // k3: stream the output, t tiled by TB for occupancy
  hipLaunchKernelGGL(out_kernel, dim3((N_DIM * 64) / 256, T_DIM / TB), dim3(256), 0,
                     stream, x, p, out);
}

// Round 3
// 529.986 us; speedup vs baseline: 1.0976x; 1.0232x over previous
//
#include <hip/hip_runtime.h>
#include <hip/hip_bf16.h>

// AttentionLayer: T=128, N=2048, D=256, w=3
// out[i] = x[i]                                  for i < 3
// out[i,n,:] = sum_j p[i-3+j,n] * x[i-3+j,n,:]   for i >= 3
// p[t,:] = softmax_n( sum_e proj[e]*tanh( (x[t] @ W)[n,e] ) )
//
// R2 changes (R2b: fix nontemporal-store type — use clang ext-vector f32x4):
//  - gemm: W fully LDS-resident (128 KB static, XOR-swizzled), staged ONCE ->
//    the entire K=256 loop runs with ZERO barriers. A prefetch deepened to
//    4 k-tiles (~1400 cyc ahead > 900 cyc HBM latency). 1 block/CU,
//    __launch_bounds__(512,2) caps VGPR at 256 (acc 128 + A 64 + misc).
//  - out: t-loop unrolled by 4 (4 x-slices in flight per wave) and
//    nontemporal stores (out never re-read; keeps x tail L3-resident).

#define T_DIM 128
#define N_DIM 2048
#define D_DIM 256
#define TS 127              // number of s/p slices (t = 0..126)
#define M_TOT (TS * N_DIM)  // 260096 rows in the fused GEMM
#define BM 256
#define TB 32

typedef __attribute__((ext_vector_type(8))) short bf16x8;
typedef __attribute__((ext_vector_type(4))) float f32x4;

__device__ inline short f2bf(float f) {
  union { float f; unsigned u; } v; v.f = f;
  unsigned r = v.u + 0x7FFFu + ((v.u >> 16) & 1u);  // round-nearest-even
  return (short)(r >> 16);
}

__device__ inline bf16x8 cvt8(const float4 a, const float4 b) {
  bf16x8 r;
  r[0] = f2bf(a.x); r[1] = f2bf(a.y); r[2] = f2bf(a.z); r[3] = f2bf(a.w);
  r[4] = f2bf(b.x); r[5] = f2bf(b.y); r[6] = f2bf(b.z); r[7] = f2bf(b.w);
  return r;
}

// tanh(x) = (e^{2x}-1)/(e^{2x}+1); clamp avoids inf/inf. |err| ~1e-7.
__device__ inline float fast_tanh(float x) {
  float e = __expf(fminf(2.0f * x, 30.0f));
  return __fdividef(e - 1.0f, e + 1.0f);
}

// ---------------- k0: W (fp32, d x e) -> Wt (bf16, e x d) ----------------
__global__ __launch_bounds__(256) void prep_kernel(const float* __restrict__ W,
                                                   short* __restrict__ Wt) {
  int id = blockIdx.x * 256 + threadIdx.x;   // 65536 total
  int d = id >> 8;
  int e = id & 255;
  Wt[e * 256 + d] = f2bf(W[d * 256 + e]);
}

// ---------------- k1: fused GEMM + tanh + proj-reduce -> s[m] ------------
// 512 threads = 8 waves, each wave owns 32 m-rows x all 256 e-cols.
// acc: 2 row-frags x 16 e-frags of 16x16x32 MFMA = 128 VGPR f32.
__global__ __launch_bounds__(512, 2) void gemm_s_kernel(const float* __restrict__ x,
                                                        const short* __restrict__ Wt,
                                                        const float* __restrict__ proj,
                                                        float* __restrict__ s) {
  __shared__ short Ws[256 * 256];  // 128 KB: ALL of W, e-major, swizzled

  const int tid = threadIdx.x;
  const int lane = tid & 63;
  const int w = tid >> 6;          // wave 0..7
  const int quad = lane >> 4;      // k-group within frag
  const int l15 = lane & 15;       // row (A) / e-col (B) within frag
  const int m0 = blockIdx.x * BM;
  const size_t row0 = (size_t)(m0 + w * 32 + l15);
  const float* xp = x + row0 * D_DIM + quad * 8;
  const int swzc = (l15 & 7) << 4;

  // 4-deep A prefetch: A[i] holds k-tile i (32 k each)
  float4 A[4][2][2];
#pragma unroll
  for (int i = 0; i < 4; ++i) {
    const float* q = xp + i * 32;
    A[i][0][0] = *(const float4*)(q);
    A[i][0][1] = *(const float4*)(q + 4);
    A[i][1][0] = *(const float4*)(q + 16 * D_DIM);
    A[i][1][1] = *(const float4*)(q + 16 * D_DIM + 4);
  }

  // stage ALL of W: 8192 x 16B slots over 512 threads.
  // dst byte = e*512 + ((ks*16) ^ ((e&7)<<4))   (XOR bank-swizzle per row)
#pragma unroll
  for (int it = 0; it < 16; ++it) {
    int slot = tid + it * 512;
    int e = slot >> 5;
    int ks = slot & 31;
    uint4 v = *(const uint4*)(Wt + e * D_DIM + ks * 8);
    int dst = e * 512 + ((ks * 16) ^ ((e & 7) << 4));
    *(uint4*)((char*)Ws + dst) = v;
  }
  __syncthreads();  // the ONLY barrier

  f32x4 acc[2][16] = {};

#pragma unroll
  for (int kg = 0; kg < 8; ++kg) {
    const bf16x8 a0 = cvt8(A[kg & 3][0][0], A[kg & 3][0][1]);
    const bf16x8 a1 = cvt8(A[kg & 3][1][0], A[kg & 3][1][1]);
    if (kg < 4) {  // refill slot kg with k-tile kg+4
      const float* q = xp + (kg + 4) * 32;
      A[kg][0][0] = *(const float4*)(q);
      A[kg][0][1] = *(const float4*)(q + 4);
      A[kg][1][0] = *(const float4*)(q + 16 * D_DIM);
      A[kg][1][1] = *(const float4*)(q + 16 * D_DIM + 4);
    }
    // B read: byte = (ef*16+l15)*512 + ((kg*64 + quad*16) ^ swzc)
    const int kb = (kg * 64 + quad * 16) ^ swzc;
#pragma unroll
    for (int ef = 0; ef < 16; ++ef) {
      const bf16x8 b =
          *(const bf16x8*)((const char*)Ws + (ef * 16 + l15) * 512 + kb);
      acc[0][ef] = __builtin_amdgcn_mfma_f32_16x16x32_bf16(a0, b, acc[0][ef], 0, 0, 0);
      acc[1][ef] = __builtin_amdgcn_mfma_f32_16x16x32_bf16(a1, b, acc[1][ef], 0, 0, 0);
    }
  }

  // epilogue: s[m] = sum_e tanh(C[m][e]) * proj[e]
  // C/D frag: e-col = ef*16 + l15, m-row = mf*16 + quad*4 + r
  float pj[16];
#pragma unroll
  for (int ef = 0; ef < 16; ++ef) pj[ef] = proj[ef * 16 + l15];

#pragma unroll
  for (int mf = 0; mf < 2; ++mf) {
#pragma unroll
    for (int r = 0; r < 4; ++r) {
      float val = 0.f;
#pragma unroll
      for (int ef = 0; ef < 16; ++ef)
        val = __builtin_fmaf(fast_tanh(acc[mf][ef][r]), pj[ef], val);
#pragma unroll
      for (int off = 1; off < 16; off <<= 1) val += __shfl_xor(val, off);
      if (l15 == 0) s[m0 + w * 32 + mf * 16 + quad * 4 + r] = val;
    }
  }
}

// ---------------- k2: softmax over n (2048) per t ------------------------
__global__ __launch_bounds__(256) void softmax_kernel(const float* __restrict__ s,
                                                      float* __restrict__ p) {
  const int t = blockIdx.x;
  const int tid = threadIdx.x;
  const float* row = s + (size_t)t * N_DIM;
  float v[8];
  float mx = -1e30f;
#pragma unroll
  for (int k = 0; k < 8; ++k) {
    v[k] = row[tid + k * 256];
    mx = fmaxf(mx, v[k]);
  }
#pragma unroll
  for (int off = 1; off < 64; off <<= 1) mx = fmaxf(mx, __shfl_xor(mx, off));
  __shared__ float redm[4];
  if ((tid & 63) == 0) redm[tid >> 6] = mx;
  __syncthreads();
  mx = fmaxf(fmaxf(redm[0], redm[1]), fmaxf(redm[2], redm[3]));

  float sum = 0.f;
#pragma unroll
  for (int k = 0; k < 8; ++k) {
    v[k] = __expf(v[k] - mx);
    sum += v[k];
  }
#pragma unroll
  for (int off = 1; off < 64; off <<= 1) sum += __shfl_xor(sum, off);
  __shared__ float reds[4];
  if ((tid & 63) == 0) reds[tid >> 6] = sum;
  __syncthreads();
  sum = reds[0] + reds[1] + reds[2] + reds[3];
  float inv = 1.0f / sum;
#pragma unroll
  for (int k = 0; k < 8; ++k) p[(size_t)t * N_DIM + tid + k * 256] = v[k] * inv;
}

// ---------------- k3: streaming output, t tiled by TB, 4-unrolled --------
__global__ __launch_bounds__(256) void out_kernel(const float* __restrict__ x,
                                                  const float* __restrict__ p,
                                                  float* __restrict__ out) {
  const int gid = blockIdx.x * 256 + threadIdx.x;  // 131072 = 2048 * 64
  const int n = gid >> 6;
  const int d4 = gid & 63;
  const int t0 = blockIdx.y * TB;
  const size_t base = (size_t)n * D_DIM + d4 * 4;
  const size_t tstride = (size_t)N_DIM * D_DIM;

  float4 x0 = {}, x1 = {}, x2 = {};
  float p0 = 0.f, p1 = 0.f, p2 = 0.f;
  if (t0 >= 3) {  // warm-up: window for the first output of this chunk
    x0 = *(const float4*)(x + (t0 - 3) * tstride + base);
    x1 = *(const float4*)(x + (t0 - 2) * tstride + base);
    x2 = *(const float4*)(x + (t0 - 1) * tstride + base);
    p0 = p[(size_t)(t0 - 3) * N_DIM + n];
    p1 = p[(size_t)(t0 - 2) * N_DIM + n];
    p2 = p[(size_t)(t0 - 1) * N_DIM + n];
  }

#define OUT_STEP(C, Q, TT)                                                     \
  {                                                                            \
    f32x4 o;                                                                   \
    if (t + TT >= 3) {                                                         \
      o[0] = p0 * x0.x + p1 * x1.x + p2 * x2.x;                                \
      o[1] = p0 * x0.y + p1 * x1.y + p2 * x2.y;                                \
      o[2] = p0 * x0.z + p1 * x1.z + p2 * x2.z;                                \
      o[3] = p0 * x0.w + p1 * x1.w + p2 * x2.w;                                \
    } else {                                                                   \
      o[0] = C.x; o[1] = C.y; o[2] = C.z; o[3] = C.w;                          \
    }                                                                          \
    __builtin_nontemporal_store(                                               \
        o, (f32x4*)(out + (size_t)(t + TT) * tstride + base));                 \
    x0 = x1; x1 = x2; x2 = C;                                                  \
    p0 = p1; p1 = p2; p2 = Q;                                                  \
  }

#pragma unroll
  for (int tt = 0; tt < TB; tt += 4) {
    const int t = t0 + tt;
    const float4 c0 = *(const float4*)(x + (size_t)(t + 0) * tstride + base);
    const float4 c1 = *(const float4*)(x + (size_t)(t + 1) * tstride + base);
    const float4 c2 = *(const float4*)(x + (size_t)(t + 2) * tstride + base);
    const float4 c3 = *(const float4*)(x + (size_t)(t + 3) * tstride + base);
    const float q0 = (t + 0 < TS) ? p[(size_t)(t + 0) * N_DIM + n] : 0.f;
    const float q1 = (t + 1 < TS) ? p[(size_t)(t + 1) * N_DIM + n] : 0.f;
    const float q2 = (t + 2 < TS) ? p[(size_t)(t + 2) * N_DIM + n] : 0.f;
    const float q3 = (t + 3 < TS) ? p[(size_t)(t + 3) * N_DIM + n] : 0.f;
    OUT_STEP(c0, q0, 0)
    OUT_STEP(c1, q1, 1)
    OUT_STEP(c2, q2, 2)
    OUT_STEP(c3, q3, 3)
  }
#undef OUT_STEP
}

extern "C" void kernel_launch(void* const* d_in, const int* in_sizes, int n_in,
                              void* d_out, int out_size, void* d_ws, size_t ws_size,
                              hipStream_t stream) {
  const float* x = (const float*)d_in[0];     // (128, 2048, 256) fp32
  const float* W = (const float*)d_in[1];     // (256, 256) fp32
  const float* proj = (const float*)d_in[2];  // (256, 1) fp32
  // d_in[3] = attention_width = 3 (hardcoded)
  float* out = (float*)d_out;

  // workspace layout
  char* ws = (char*)d_ws;
  short* Wt = (short*)ws;                               // 65536 bf16 = 128 KB
  float* s = (float*)(ws + 131072);                     // 260096 f32 ~ 1 MB
  float* p = (float*)(ws + 131072 + 1040384);           // 260096 f32 ~ 1 MB

  // k0: transpose+convert W (s is fully overwritten by k1 -> no memset)
  hipLaunchKernelGGL(prep_kernel, dim3(256), dim3(256), 0, stream, W, Wt);

  // k1: s[t,n] = sum_e proj[e]*tanh((x[t] @ W)[n,e])
  hipLaunchKernelGGL(gemm_s_kernel, dim3(M_TOT / BM), dim3(512), 0, stream,
                     x, Wt, proj, s);

  // k2: p[t,:] = softmax_n(s[t,:])
  hipLaunchKernelGGL(softmax_kernel, dim3(TS), dim3(256), 0, stream, s, p);

  // k3: stream the output, t tiled by TB for occupancy
  hipLaunchKernelGGL(out_kernel, dim3((N_DIM * 64) / 256, T_DIM / TB), dim3(256), 0,
                     stream, x, p, out);
}